// Round 2
// baseline (467.080 us; speedup 1.0000x reference)
//
#include <hip/hip_runtime.h>
#include <cstdint>

#define K_DIM 3072
#define B_DIM 8192
#define BM    128
#define NT    64   /* 8192/128 tiles per dim */
#define ROW_U 384  /* u32 per row of fp4-packed x: 3072 * 4bit / 32bit */

typedef __attribute__((ext_vector_type(4))) float        f32x4;
typedef __attribute__((ext_vector_type(4))) unsigned int u32x4;
typedef __attribute__((ext_vector_type(8))) int          i32x8;

// f32 -> fp4 e2m1 nibble (RNE to nearest representable {0,.5,1,1.5,2,3,4,6})
__device__ __forceinline__ unsigned f2fp4(float f) {
    unsigned s = (__float_as_uint(f) >> 31) << 3;
    float a = fabsf(f);
    unsigned m;
    if      (a < 0.25f) m = 0;
    else if (a < 0.75f) m = 1;
    else if (a < 1.25f) m = 2;
    else if (a < 1.75f) m = 3;
    else if (a < 2.5f)  m = 4;
    else if (a < 3.5f)  m = 5;
    else if (a < 5.0f)  m = 6;
    else                m = 7;
    return s | m;
}

// ---------- kernel 1: pack x into fp4 + row sum-of-squares (f32 exact) ----------
__global__ __launch_bounds__(384) void prep_kernel(const float* __restrict__ x,
                                                   unsigned int* __restrict__ xb,
                                                   float* __restrict__ xn,
                                                   float* __restrict__ se)
{
    const int row = blockIdx.x;
    const int tid = threadIdx.x;            // 384 threads, 8 f32 -> 1 u32 each
    const float4* xr = (const float4*)(x + (size_t)row * K_DIM);
    float4 v0 = xr[2 * tid];
    float4 v1 = xr[2 * tid + 1];
    float s = v0.x * v0.x + v0.y * v0.y + v0.z * v0.z + v0.w * v0.w
            + v1.x * v1.x + v1.y * v1.y + v1.z * v1.z + v1.w * v1.w;
    unsigned w =  f2fp4(v0.x)
               | (f2fp4(v0.y) << 4)
               | (f2fp4(v0.z) << 8)
               | (f2fp4(v0.w) << 12)
               | (f2fp4(v1.x) << 16)
               | (f2fp4(v1.y) << 20)
               | (f2fp4(v1.z) << 24)
               | (f2fp4(v1.w) << 28);
    xb[(size_t)row * ROW_U + tid] = w;

#pragma unroll
    for (int d = 32; d > 0; d >>= 1) s += __shfl_down(s, d);
    __shared__ float red[6];
    if ((tid & 63) == 0) red[tid >> 6] = s;
    __syncthreads();
    if (tid == 0) {
        float t = 0.f;
#pragma unroll
        for (int i = 0; i < 6; ++i) t += red[i];
        xn[row] = t;
        se[row] = 0.f;
    }
}

// ---------- kernel 2: triangular MX-fp4 Gram tiles + fused exp row/col sums ----------
__global__ __launch_bounds__(256) void gram_lse_kernel(const unsigned int* __restrict__ xb,
                                                       const float* __restrict__ xn,
                                                       const float* __restrict__ logvar,
                                                       float* __restrict__ se)
{
    __shared__ __align__(1024) unsigned int lA[BM * 16];  // 128 rows x 64 B
    __shared__ __align__(1024) unsigned int lB[BM * 16];

    // decode linear block id -> triangular tile (bm <= bn)
    int rem = blockIdx.x;
    int bm = 0;
    while (rem >= NT - bm) { rem -= NT - bm; ++bm; }
    const int bn = bm + rem;

    const int tid  = threadIdx.x;
    const int lane = tid & 63;
    const int wave = tid >> 6;
    const int wr = wave >> 1, wc = wave & 1;

    const size_t rowA0 = (size_t)bm * BM;
    const size_t rowB0 = (size_t)bn * BM;

    // staging: each wave stages 32 rows of each tile (2 instrs x 16 rows);
    // lane carries row sRow, 16B chunk (lane&3) of the 64B k-slab
    const int sRow  = wave * 32 + (lane >> 2);
    const int sColU = (lane & 3) * 4;                   // u32 units (16 B)
    const unsigned int* gA = xb + (rowA0 + sRow) * ROW_U + sColU;
    const unsigned int* gB = xb + (rowB0 + sRow) * ROW_U + sColU;
    unsigned int* lA0 = &lA[wave * 32 * 16];            // wave-uniform LDS base
    unsigned int* lB0 = &lB[wave * 32 * 16];

    f32x4 acc[4][4];
#pragma unroll
    for (int i = 0; i < 4; ++i)
#pragma unroll
        for (int j = 0; j < 4; ++j) acc[i][j] = (f32x4){0.f, 0.f, 0.f, 0.f};

    const int aRow  = wr * 64 + (lane & 15);
    const int bRow  = wc * 64 + (lane & 15);
    const int kOffU = (lane >> 4) * 4;                  // 16B k-chunk per lane-group

    for (int kt = 0; kt < K_DIM / 128; ++kt) {          // 24 iters, 128 fp4-k each
        const int kg = kt * 16;                         // u32 per row per chunk
        __syncthreads();   // previous iter's LDS reads done before overwrite
#pragma unroll
        for (int i = 0; i < 2; ++i) {
            __builtin_amdgcn_global_load_lds(
                (__attribute__((address_space(1))) void*)(gA + (size_t)(i * 16) * ROW_U + kg),
                (__attribute__((address_space(3))) void*)(lA0 + i * 16 * 16), 16, 0, 0);
            __builtin_amdgcn_global_load_lds(
                (__attribute__((address_space(1))) void*)(gB + (size_t)(i * 16) * ROW_U + kg),
                (__attribute__((address_space(3))) void*)(lB0 + i * 16 * 16), 16, 0, 0);
        }
        __syncthreads();   // drains vmcnt(0): LDS tiles ready

        i32x8 aF[4], bF[4];
#pragma unroll
        for (int mi = 0; mi < 4; ++mi) {
            u32x4 t = *(const u32x4*)&lA[(aRow + mi * 16) * 16 + kOffU];
            i32x8 f;
            f[0] = (int)t[0]; f[1] = (int)t[1]; f[2] = (int)t[2]; f[3] = (int)t[3];
            f[4] = 0; f[5] = 0; f[6] = 0; f[7] = 0;
            aF[mi] = f;
        }
#pragma unroll
        for (int ni = 0; ni < 4; ++ni) {
            u32x4 t = *(const u32x4*)&lB[(bRow + ni * 16) * 16 + kOffU];
            i32x8 f;
            f[0] = (int)t[0]; f[1] = (int)t[1]; f[2] = (int)t[2]; f[3] = (int)t[3];
            f[4] = 0; f[5] = 0; f[6] = 0; f[7] = 0;
            bF[ni] = f;
        }
#pragma unroll
        for (int mi = 0; mi < 4; ++mi)
#pragma unroll
            for (int ni = 0; ni < 4; ++ni)
                acc[mi][ni] = __builtin_amdgcn_mfma_scale_f32_16x16x128_f8f6f4(
                    aF[mi], bF[ni], acc[mi][ni],
                    4, 4,          /* cbsz=fp4, blgp=fp4 */
                    0, 127,        /* A scale: e8m0 127 = 1.0 */
                    0, 127);       /* B scale */
    }

    // ---- fused epilogue: exp terms + row/col partial sums ----
    const float lv  = logvar[0];
    const float var = __expf(lv) + 1e-10f;
    const float cc  = 0.5f / var;

    const int colBase = (int)rowB0 + wc * 64 + (lane & 15);
    const int rowBase = (int)rowA0 + wr * 64 + (lane >> 4) * 4;

    // row sums -> se[i], i in bm tile rows
#pragma unroll
    for (int mi = 0; mi < 4; ++mi) {
#pragma unroll
        for (int r = 0; r < 4; ++r) {
            const int i = rowBase + mi * 16 + r;
            const float xni = xn[i];
            float rs = 0.f;
#pragma unroll
            for (int ni = 0; ni < 4; ++ni) {
                const int j = colBase + ni * 16;
                const float g = acc[mi][ni][r];
                const float dist = xni + xn[j] - 2.f * g;
                rs += (i == j) ? 1.0f : __expf(-cc * fmaxf(dist, 0.f));
            }
#pragma unroll
            for (int d = 1; d < 16; d <<= 1) rs += __shfl_xor(rs, d);
            if ((lane & 15) == 0) atomicAdd(&se[i], rs);
        }
    }

    // col sums -> se[j] for off-diagonal tiles (mirror elements, i != j always)
    if (bm != bn) {
#pragma unroll
        for (int ni = 0; ni < 4; ++ni) {
            const int j = colBase + ni * 16;
            const float xnj = xn[j];
            float cs = 0.f;
#pragma unroll
            for (int mi = 0; mi < 4; ++mi) {
#pragma unroll
                for (int r = 0; r < 4; ++r) {
                    const int i = rowBase + mi * 16 + r;
                    const float g = acc[mi][ni][r];
                    cs += __expf(-cc * fmaxf(xn[i] + xnj - 2.f * g, 0.f));
                }
            }
#pragma unroll
            for (int d = 16; d < 64; d <<= 1) cs += __shfl_xor(cs, d);
            if ((lane >> 4) == 0) atomicAdd(&se[j], cs);
        }
    }
}

// ---------- kernel 3: KL scalar ----------
__global__ __launch_bounds__(256) void kl_kernel(const float* __restrict__ se,
                                                 float* __restrict__ out)
{
    const int tid = threadIdx.x;
    float s = 0.f;
    for (int i = tid; i < B_DIM; i += 256) s += logf(se[i]);
#pragma unroll
    for (int d = 32; d > 0; d >>= 1) s += __shfl_down(s, d);
    __shared__ float red[4];
    if ((tid & 63) == 0) red[tid >> 6] = s;
    __syncthreads();
    if (tid == 0) {
        const float dc = -(red[0] + red[1] + red[2] + red[3]) / (float)B_DIM;
        out[0] = (logf((float)B_DIM) + dc) / logf(2.f);
    }
}

// ---------- kernel 4: x_t = x + exp(0.5*logvar) * noise ----------
__global__ __launch_bounds__(256) void xt_kernel(const float4* __restrict__ x,
                                                 const float4* __restrict__ nz,
                                                 const float* __restrict__ logvar,
                                                 float4* __restrict__ out, int n4)
{
    const float sc = expf(0.5f * logvar[0]);
    for (int i = blockIdx.x * blockDim.x + threadIdx.x; i < n4;
         i += gridDim.x * blockDim.x) {
        float4 a = x[i], b = nz[i];
        float4 o;
        o.x = fmaf(sc, b.x, a.x);
        o.y = fmaf(sc, b.y, a.y);
        o.z = fmaf(sc, b.z, a.z);
        o.w = fmaf(sc, b.w, a.w);
        out[i] = o;
    }
}

extern "C" void kernel_launch(void* const* d_in, const int* in_sizes, int n_in,
                              void* d_out, int out_size, void* d_ws, size_t ws_size,
                              hipStream_t stream)
{
    const float* x      = (const float*)d_in[0];
    const float* noise  = (const float*)d_in[1];
    const float* logvar = (const float*)d_in[2];
    float* out = (float*)d_out;

    const size_t NEL = (size_t)B_DIM * K_DIM;   // 25165824

    // scratch carved out of d_out (fully overwritten by xt_kernel at the end):
    //   bytes [0, 12.6MB)  : fp4-packed x (8192 rows x 384 u32)
    //   bytes [32MB, ...)  : x_norm (f32, 8192) then sumexp (f32, 8192)
    unsigned int* xb = (unsigned int*)d_out;
    float* xn = (float*)((char*)d_out + (32u << 20));
    float* se = xn + B_DIM;

    prep_kernel<<<B_DIM, 384, 0, stream>>>(x, xb, xn, se);

    const int ntri = NT * (NT + 1) / 2;   // 2080 triangular tiles
    gram_lse_kernel<<<ntri, 256, 0, stream>>>(xb, xn, logvar, se);

    kl_kernel<<<1, 256, 0, stream>>>(se, out + NEL);

    xt_kernel<<<2048, 256, 0, stream>>>((const float4*)x, (const float4*)noise,
                                        logvar, (float4*)out, (int)(NEL / 4));
}

// Round 3
// 317.407 us; speedup vs baseline: 1.4716x; 1.4716x over previous
//
#include <hip/hip_runtime.h>
#include <cstdint>

#define K_DIM 3072
#define B_DIM 8192
#define BM    128
#define NT    64      /* 8192/128 tiles per dim */
#define ROW_B 3072    /* bytes per fp8 row */
#define ROW_U 768     /* u32 per fp8 row */

typedef __attribute__((ext_vector_type(4))) float        f32x4;
typedef __attribute__((ext_vector_type(4))) unsigned int u32x4;
typedef long long i64;

__device__ __forceinline__ i64 pack64(unsigned lo, unsigned hi) {
    return (i64)(((unsigned long long)hi << 32) | (unsigned long long)lo);
}

// ---------- kernel 1: pack x into fp8 e4m3 (k-octets permuted) + row |x|^2 ----------
// k-permutation within each 64-k block: dest bytes [c*16+0..7] = k[c*8..c*8+7],
// dest bytes [c*16+8..15] = k[32+c*8 .. 32+c*8+7].  Same permutation for A and B
// operands of the Gram => dot products invariant.
__global__ __launch_bounds__(384) void prep_kernel(const float* __restrict__ x,
                                                   unsigned int* __restrict__ xb,
                                                   float* __restrict__ xn,
                                                   float* __restrict__ se)
{
    const int row = blockIdx.x;
    const int tid = threadIdx.x;            // 384 threads: one k-octet (8 floats) each
    const float4* xr = (const float4*)(x + (size_t)row * K_DIM);
    float4 v0 = xr[2 * tid];
    float4 v1 = xr[2 * tid + 1];
    float s = v0.x * v0.x + v0.y * v0.y + v0.z * v0.z + v0.w * v0.w
            + v1.x * v1.x + v1.y * v1.y + v1.z * v1.z + v1.w * v1.w;

    int p0 = __builtin_amdgcn_cvt_pk_fp8_f32(v0.x, v0.y, 0, false);
    p0     = __builtin_amdgcn_cvt_pk_fp8_f32(v0.z, v0.w, p0, true);
    int p1 = __builtin_amdgcn_cvt_pk_fp8_f32(v1.x, v1.y, 0, false);
    p1     = __builtin_amdgcn_cvt_pk_fp8_f32(v1.z, v1.w, p1, true);

    const int blk = tid >> 3;               // 64-k block index (0..47)
    const int oct = tid & 7;                // octet within block
    const int offB = blk * 64 + ((oct < 4) ? oct * 16 : (oct - 4) * 16 + 8);
    unsigned int* dst = xb + (size_t)row * ROW_U + (offB >> 2);
    dst[0] = (unsigned)p0;
    dst[1] = (unsigned)p1;

#pragma unroll
    for (int d = 32; d > 0; d >>= 1) s += __shfl_down(s, d);
    __shared__ float red[6];
    if ((tid & 63) == 0) red[tid >> 6] = s;
    __syncthreads();
    if (tid == 0) {
        float t = 0.f;
#pragma unroll
        for (int i = 0; i < 6; ++i) t += red[i];
        xn[row] = t;
        se[row] = 0.f;
    }
}

// ---------- kernel 2: triangular fp8 Gram tiles + fused exp row/col sums ----------
__global__ __launch_bounds__(256) void gram_lse_kernel(const unsigned int* __restrict__ xb,
                                                       const float* __restrict__ xn,
                                                       const float* __restrict__ logvar,
                                                       float* __restrict__ se)
{
    __shared__ __align__(1024) unsigned int lA[BM * 16];  // 128 rows x 64 B (one K=64 slab)
    __shared__ __align__(1024) unsigned int lB[BM * 16];

    // decode linear block id -> triangular tile (bm <= bn)
    int rem = blockIdx.x;
    int bm = 0;
    while (rem >= NT - bm) { rem -= NT - bm; ++bm; }
    const int bn = bm + rem;

    const int tid  = threadIdx.x;
    const int lane = tid & 63;
    const int wave = tid >> 6;
    const int wr = wave >> 1, wc = wave & 1;

    const size_t rowA0 = (size_t)bm * BM;
    const size_t rowB0 = (size_t)bn * BM;

    // staging: wave stages 32 rows/tile (2 instrs x 16 rows); lane carries
    // row sRow, 16B chunk (lane&3).  Source chunk index is PRE-SWIZZLED
    // (XOR (sRow>>1)&3) so that linear LDS writes land swizzled (rule #21).
    const int sRow = wave * 32 + (lane >> 2);
    const int csw  = (lane & 3) ^ ((sRow >> 1) & 3);
    const unsigned char* xb8 = (const unsigned char*)xb;
    const unsigned char* gA = xb8 + (rowA0 + sRow) * ROW_B + csw * 16;
    const unsigned char* gB = xb8 + (rowB0 + sRow) * ROW_B + csw * 16;
    unsigned int* lA0 = &lA[wave * 32 * 16];            // wave-uniform LDS base
    unsigned int* lB0 = &lB[wave * 32 * 16];

    f32x4 acc[4][4];
#pragma unroll
    for (int i = 0; i < 4; ++i)
#pragma unroll
        for (int j = 0; j < 4; ++j) acc[i][j] = (f32x4){0.f, 0.f, 0.f, 0.f};

    const int fRowA = wr * 64 + (lane & 15);
    const int fRowB = wc * 64 + (lane & 15);
    const int fc    = lane >> 4;            // logical 16B chunk (holds both k-half frags)

    for (int kt = 0; kt < K_DIM / 64; ++kt) {           // 48 iters, K=64 each
        const int kg = kt * 64;                         // byte offset within row
        __syncthreads();   // previous iter's LDS reads done before overwrite
#pragma unroll
        for (int i = 0; i < 2; ++i) {
            __builtin_amdgcn_global_load_lds(
                (const __attribute__((address_space(1))) void*)(gA + (size_t)(i * 16) * ROW_B + kg),
                (__attribute__((address_space(3))) void*)(lA0 + i * 16 * 16), 16, 0, 0);
            __builtin_amdgcn_global_load_lds(
                (const __attribute__((address_space(1))) void*)(gB + (size_t)(i * 16) * ROW_B + kg),
                (__attribute__((address_space(3))) void*)(lB0 + i * 16 * 16), 16, 0, 0);
        }
        __syncthreads();   // drains vmcnt(0): LDS tiles ready

        i64 aLo[4], aHi[4], bLo[4], bHi[4];
#pragma unroll
        for (int mi = 0; mi < 4; ++mi) {
            const int row = fRowA + mi * 16;
            const int phys = fc ^ ((row >> 1) & 3);     // swizzled read
            u32x4 t = *(const u32x4*)&lA[row * 16 + phys * 4];
            aLo[mi] = pack64(t[0], t[1]);               // k-half 0 (octets 0..3 perm)
            aHi[mi] = pack64(t[2], t[3]);               // k-half 1
        }
#pragma unroll
        for (int ni = 0; ni < 4; ++ni) {
            const int row = fRowB + ni * 16;
            const int phys = fc ^ ((row >> 1) & 3);
            u32x4 t = *(const u32x4*)&lB[row * 16 + phys * 4];
            bLo[ni] = pack64(t[0], t[1]);
            bHi[ni] = pack64(t[2], t[3]);
        }
#pragma unroll
        for (int mi = 0; mi < 4; ++mi)
#pragma unroll
            for (int ni = 0; ni < 4; ++ni) {
                acc[mi][ni] = __builtin_amdgcn_mfma_f32_16x16x32_fp8_fp8(
                    aLo[mi], bLo[ni], acc[mi][ni], 0, 0, 0);
                acc[mi][ni] = __builtin_amdgcn_mfma_f32_16x16x32_fp8_fp8(
                    aHi[mi], bHi[ni], acc[mi][ni], 0, 0, 0);
            }
    }

    // ---- fused epilogue: exp terms + row/col partial sums ----
    const float lv  = logvar[0];
    const float var = __expf(lv) + 1e-10f;
    const float cc  = 0.5f / var;

    const int colBase = (int)rowB0 + wc * 64 + (lane & 15);
    const int rowBase = (int)rowA0 + wr * 64 + (lane >> 4) * 4;

    // row sums -> se[i]
#pragma unroll
    for (int mi = 0; mi < 4; ++mi) {
#pragma unroll
        for (int r = 0; r < 4; ++r) {
            const int i = rowBase + mi * 16 + r;
            const float xni = xn[i];
            float rs = 0.f;
#pragma unroll
            for (int ni = 0; ni < 4; ++ni) {
                const int j = colBase + ni * 16;
                const float g = acc[mi][ni][r];
                const float dist = xni + xn[j] - 2.f * g;
                rs += (i == j) ? 1.0f : __expf(-cc * fmaxf(dist, 0.f));
            }
#pragma unroll
            for (int d = 1; d < 16; d <<= 1) rs += __shfl_xor(rs, d);
            if ((lane & 15) == 0) atomicAdd(&se[i], rs);
        }
    }

    // col sums -> se[j] for off-diagonal tiles (mirror elements, i != j always)
    if (bm != bn) {
#pragma unroll
        for (int ni = 0; ni < 4; ++ni) {
            const int j = colBase + ni * 16;
            const float xnj = xn[j];
            float cs = 0.f;
#pragma unroll
            for (int mi = 0; mi < 4; ++mi) {
#pragma unroll
                for (int r = 0; r < 4; ++r) {
                    const int i = rowBase + mi * 16 + r;
                    const float g = acc[mi][ni][r];
                    cs += __expf(-cc * fmaxf(xn[i] + xnj - 2.f * g, 0.f));
                }
            }
#pragma unroll
            for (int d = 16; d < 64; d <<= 1) cs += __shfl_xor(cs, d);
            if ((lane >> 4) == 0) atomicAdd(&se[j], cs);
        }
    }
}

// ---------- kernel 3: KL scalar ----------
__global__ __launch_bounds__(256) void kl_kernel(const float* __restrict__ se,
                                                 float* __restrict__ out)
{
    const int tid = threadIdx.x;
    float s = 0.f;
    for (int i = tid; i < B_DIM; i += 256) s += logf(se[i]);
#pragma unroll
    for (int d = 32; d > 0; d >>= 1) s += __shfl_down(s, d);
    __shared__ float red[4];
    if ((tid & 63) == 0) red[tid >> 6] = s;
    __syncthreads();
    if (tid == 0) {
        const float dc = -(red[0] + red[1] + red[2] + red[3]) / (float)B_DIM;
        out[0] = (logf((float)B_DIM) + dc) / logf(2.f);
    }
}

// ---------- kernel 4: x_t = x + exp(0.5*logvar) * noise ----------
__global__ __launch_bounds__(256) void xt_kernel(const float4* __restrict__ x,
                                                 const float4* __restrict__ nz,
                                                 const float* __restrict__ logvar,
                                                 float4* __restrict__ out, int n4)
{
    const float sc = expf(0.5f * logvar[0]);
    for (int i = blockIdx.x * blockDim.x + threadIdx.x; i < n4;
         i += gridDim.x * blockDim.x) {
        float4 a = x[i], b = nz[i];
        float4 o;
        o.x = fmaf(sc, b.x, a.x);
        o.y = fmaf(sc, b.y, a.y);
        o.z = fmaf(sc, b.z, a.z);
        o.w = fmaf(sc, b.w, a.w);
        out[i] = o;
    }
}

extern "C" void kernel_launch(void* const* d_in, const int* in_sizes, int n_in,
                              void* d_out, int out_size, void* d_ws, size_t ws_size,
                              hipStream_t stream)
{
    const float* x      = (const float*)d_in[0];
    const float* noise  = (const float*)d_in[1];
    const float* logvar = (const float*)d_in[2];
    float* out = (float*)d_out;

    const size_t NEL = (size_t)B_DIM * K_DIM;   // 25165824

    // scratch carved out of d_out (fully overwritten by xt_kernel at the end):
    //   bytes [0, 25.2MB)  : fp8-packed x (8192 rows x 3072 B, k-octets permuted)
    //   bytes [32MB, ...)  : x_norm (f32, 8192) then sumexp (f32, 8192)
    unsigned int* xb = (unsigned int*)d_out;
    float* xn = (float*)((char*)d_out + (32u << 20));
    float* se = xn + B_DIM;

    prep_kernel<<<B_DIM, 384, 0, stream>>>(x, xb, xn, se);

    const int ntri = NT * (NT + 1) / 2;   // 2080 triangular tiles
    gram_lse_kernel<<<ntri, 256, 0, stream>>>(xb, xn, logvar, se);

    kl_kernel<<<1, 256, 0, stream>>>(se, out + NEL);

    xt_kernel<<<2048, 256, 0, stream>>>((const float4*)x, (const float4*)noise,
                                        logvar, (float4*)out, (int)(NEL / 4));
}